// Round 3
// baseline (5468.224 us; speedup 1.0000x reference)
//
#include <hip/hip_runtime.h>
#include <hip/hip_bf16.h>

#define TT 512
#define BB 128
#define II 256
#define HH 512

#define NGROUP 8    // batch groups of 16 rows (wg&7 -> XCD affinity heuristic)
#define WPG    16   // workgroups per group; each WG = 4 waves = 2 col-halves x 2 K-halves
#define NWG    (NGROUP * WPG)

typedef __attribute__((ext_vector_type(8))) unsigned short ushort8;
typedef __attribute__((ext_vector_type(8))) __bf16         bf16x8;
typedef __attribute__((ext_vector_type(4))) float          float4v;
typedef unsigned long long u64;

union frag8 { ushort8 u; bf16x8 b; u64 q[2]; };

__device__ __forceinline__ unsigned short f2bf(float f) {
    union { float f; unsigned u; } v; v.f = f;
    return (unsigned short)((v.u + 0x7FFFu + ((v.u >> 16) & 1u)) >> 16);  // RNE
}
__device__ __forceinline__ float bf2f(unsigned short h) {
    union { unsigned u; float f; } v; v.u = ((unsigned)h) << 16;
    return v.f;
}
__device__ __forceinline__ float tanh_fast(float x) {
    float e = __expf(2.0f * x);          // robust at +-large
    return 1.0f - 2.0f / (e + 1.0f);
}
__device__ __forceinline__ float4v mfma(bf16x8 a, bf16x8 b, float4v c) {
    return __builtin_amdgcn_mfma_f32_16x16x32_bf16(a, b, c, 0, 0, 0);
}
// agent-coherent 8B exchange ops: bypass (non-coherent) L1/L2 -> no fences needed
__device__ __forceinline__ u64 ald(const unsigned short* p) {
    return __hip_atomic_load((u64*)(void*)p, __ATOMIC_RELAXED, __HIP_MEMORY_SCOPE_AGENT);
}
__device__ __forceinline__ void ast(unsigned short* p, u64 v) {
    __hip_atomic_store((u64*)(void*)p, v, __ATOMIC_RELAXED, __HIP_MEMORY_SCOPE_AGENT);
}

__global__ __launch_bounds__(256, 1) void rnn_fused(
    const float* __restrict__ Xt,   // [T][B][I]
    const float* __restrict__ W1,   // [768][512]
    const float* __restrict__ b1,   // [512]
    const float* __restrict__ W2,   // [1024][512]
    const float* __restrict__ b2,   // [512]
    float* __restrict__ out,        // [T][B][H] ++ [2][B][H]
    unsigned short* __restrict__ Ybuf,  // Y1[2][B*H] then Y2[2][B*H], bf16 bits
    unsigned int* __restrict__ cnt)     // [NGROUP][1024] per-step arrival counters
{
    const int wg  = blockIdx.x;
    const int g   = wg & 7;
    const int j   = wg >> 3;       // 0..15: 32-col block
    const int tid = threadIdx.x;
    const int w   = tid >> 6;
    const int c   = w & 1;         // col half (16 cols)
    const int kh  = w >> 1;        // K half
    const int l   = tid & 63;
    const int lr  = l & 15;
    const int lq  = l >> 4;
    const int n0  = j * 32 + c * 16;
    const int row0 = g * 16;

    unsigned short* Y1 = Ybuf;
    unsigned short* Y2 = Ybuf + 2 * BB * HH;

    __shared__ float lp1[2][64][4];                    // kh=1 -> kh=0: layer-1 partials
    __shared__ float lp2[2][64][4];                    // kh=0 -> kh=1: layer-2 partials
    __shared__ __align__(8) unsigned short tr[4][16][20];  // per-wave C-tile transpose

    // ---- persistent weight fragments (hi + lo bf16 split) ----
    // kh=0: W1 rows 0..383,  W2 rows 0..511 ; kh=1: W1 rows 384..767, W2 rows 512..1023
    frag8 w1h[12], w1l[12], w2h[16], w2l[16];
    const int kb1 = kh * 12, kb2 = kh * 16;
#pragma unroll
    for (int q = 0; q < 12; ++q)
#pragma unroll
        for (int e = 0; e < 8; ++e) {
            float v = W1[((kb1 + q) * 32 + lq * 8 + e) * HH + n0 + lr];
            unsigned short hi = f2bf(v);
            w1h[q].u[e] = hi;
            w1l[q].u[e] = f2bf(v - bf2f(hi));
        }
#pragma unroll
    for (int q = 0; q < 16; ++q)
#pragma unroll
        for (int e = 0; e < 8; ++e) {
            float v = W2[((kb2 + q) * 32 + lq * 8 + e) * HH + n0 + lr];
            unsigned short hi = f2bf(v);
            w2h[q].u[e] = hi;
            w2l[q].u[e] = f2bf(v - bf2f(hi));
        }
    const float bias1 = b1[n0 + lr];
    const float bias2 = b2[n0 + lr];

    // Pipelined: interval t computes y1(t) [layer1] and y2(t-1) [layer2].
#pragma unroll 1
    for (int t = 0; t <= TT; ++t) {
        const int par = t & 1;
        const unsigned short* y1r = Y1 + (par ^ 1) * (BB * HH);  // y1(t-1)
        const unsigned short* y2r = Y2 + par * (BB * HH);        // y2(t-2)
        unsigned short* y1w = Y1 + par * (BB * HH);
        unsigned short* y2w = Y2 + (par ^ 1) * (BB * HH);

        // ---- issue all cross-WG loads up front (agent-scope, IF$-coherent) ----
        frag8 a1[16], a2[16];
        if (kh == 0) {
#pragma unroll
            for (int q = 0; q < 16; ++q) {
                const unsigned short* p = y1r + (row0 + lr) * HH + q * 32 + lq * 8;
                a1[q].q[0] = ald(p); a1[q].q[1] = ald(p + 4);
            }
        } else {
#pragma unroll
            for (int q = 4; q < 16; ++q) {
                const unsigned short* p = y1r + (row0 + lr) * HH + q * 32 + lq * 8;
                a1[q].q[0] = ald(p); a1[q].q[1] = ald(p + 4);
            }
            if (t >= 1) {
#pragma unroll
                for (int q = 0; q < 16; ++q) {
                    const unsigned short* p = y2r + (row0 + lr) * HH + q * 32 + lq * 8;
                    a2[q].q[0] = ald(p); a2[q].q[1] = ald(p + 4);
                }
            }
        }

        // hi and lo products on independent accumulator chains
        float4v acc1  = {bias1, bias1, bias1, bias1};   // used as L1 chain (kh=0 holds bias)
        float4v acc1b = {0.f, 0.f, 0.f, 0.f};
        float4v acc2  = {bias2, bias2, bias2, bias2};   // L2 chain (kh=1 holds bias)
        float4v acc2b = {0.f, 0.f, 0.f, 0.f};
        if (kh == 0) acc2 = acc1b;     // kh=0's L2 partial has no bias
        else         acc1 = acc1b;     // kh=1's L1 partial has no bias

        if (kh == 0) {
            if (t < TT) {  // L1 partial: x(t) (k 0..255) + a1[0..3] (k 256..383)
#pragma unroll
                for (int q = 0; q < 8; ++q) {
                    const float* xp = Xt + ((size_t)t * BB + row0 + lr) * II + q * 32 + lq * 8;
                    float4v x0 = *(const float4v*)xp;
                    float4v x1 = *(const float4v*)(xp + 4);
                    frag8 ax;
#pragma unroll
                    for (int e = 0; e < 4; ++e) { ax.u[e] = f2bf(x0[e]); ax.u[4 + e] = f2bf(x1[e]); }
                    acc1  = mfma(ax.b, w1h[q].b, acc1);
                    acc1b = mfma(ax.b, w1l[q].b, acc1b);
                }
#pragma unroll
                for (int q = 0; q < 4; ++q) {
                    acc1  = mfma(a1[q].b, w1h[8 + q].b, acc1);
                    acc1b = mfma(a1[q].b, w1l[8 + q].b, acc1b);
                }
            }
            if (t >= 1) {  // L2 partial: y1(t-1) over k 0..511
#pragma unroll
                for (int q = 0; q < 16; ++q) {
                    acc2  = mfma(a1[q].b, w2h[q].b, acc2);
                    acc2b = mfma(a1[q].b, w2l[q].b, acc2b);
                }
            }
        } else {
            if (t < TT) {  // L1 partial: a1[4..15] (k 384..767)
#pragma unroll
                for (int q = 0; q < 12; ++q) {
                    acc1  = mfma(a1[4 + q].b, w1h[q].b, acc1);
                    acc1b = mfma(a1[4 + q].b, w1l[q].b, acc1b);
                }
            }
            if (t >= 1) {  // L2 partial: y2(t-2) over k 512..1023
#pragma unroll
                for (int q = 0; q < 16; ++q) {
                    acc2  = mfma(a2[q].b, w2h[q].b, acc2);
                    acc2b = mfma(a2[q].b, w2l[q].b, acc2b);
                }
            }
        }

        // ---- cross-kh partial exchange: kh=1 hands off L1, kh=0 hands off L2 ----
        if (kh == 1 && t < TT)  *(float4v*)&lp1[c][l][0] = acc1 + acc1b;
        if (kh == 0 && t >= 1)  *(float4v*)&lp2[c][l][0] = acc2 + acc2b;
        __syncthreads();

        float yout[4];  // finals kept for post-flag out writes
        if (kh == 0 && t < TT) {         // finish layer 1
            float4v p = *(const float4v*)&lp1[c][l][0];
#pragma unroll
            for (int i = 0; i < 4; ++i) {
                float y = tanh_fast(acc1[i] + acc1b[i] + p[i]);
                tr[w][lq * 4 + i][lr] = f2bf(y);
                yout[i] = y;
            }
        }
        if (kh == 1 && t >= 1) {         // finish layer 2
            float4v p = *(const float4v*)&lp2[c][l][0];
#pragma unroll
            for (int i = 0; i < 4; ++i) {
                float y = tanh_fast(acc2[i] + acc2b[i] + p[i]);
                tr[w][lq * 4 + i][lr] = f2bf(y);
                yout[i] = y;
            }
        }
        // wave-local transpose read -> contiguous 8B agent-coherent exchange store
        {
            const int row = l & 15, ch = l >> 4;
            if (kh == 0 && t < TT) {
                u64 v = *(const u64*)&tr[w][row][ch * 4];
                ast(y1w + (row0 + row) * HH + n0 + ch * 4, v);
            }
            if (kh == 1 && t >= 1) {
                u64 v = *(const u64*)&tr[w][row][ch * 4];
                ast(y2w + (row0 + row) * HH + n0 + ch * 4, v);
            }
        }

        // each wave drains its own exchange stores (vmcnt 0) before s_barrier
        asm volatile("s_waitcnt vmcnt(0) lgkmcnt(0)" ::: "memory");
        __syncthreads();

        // flag first (no cache maintenance: data already agent-coherent) ...
        if (t < TT && tid == 0)
            __hip_atomic_fetch_add(cnt + g * 1024 + t, 1u, __ATOMIC_RELAXED,
                                   __HIP_MEMORY_SCOPE_AGENT);

        // ... then output writes drain during the spin (no consumer until kernel end)
        if (kh == 1 && t >= 1) {
#pragma unroll
            for (int i = 0; i < 4; ++i) {
                const int r = row0 + lq * 4 + i;
                __builtin_nontemporal_store(yout[i], &out[((size_t)(t - 1) * BB + r) * HH + n0 + lr]);
                if (t == TT)  // hidden[1] = final h2
                    __builtin_nontemporal_store(yout[i],
                        &out[(size_t)TT * BB * HH + (size_t)BB * HH + (size_t)r * HH + n0 + lr]);
            }
        }
        if (kh == 0 && t == TT - 1) {  // hidden[0] = final h1
#pragma unroll
            for (int i = 0; i < 4; ++i) {
                const int r = row0 + lq * 4 + i;
                __builtin_nontemporal_store(yout[i],
                    &out[(size_t)TT * BB * HH + (size_t)r * HH + n0 + lr]);
            }
        }

        if (t < TT) {
            if (tid == 0) {
                while (__hip_atomic_load(cnt + g * 1024 + t, __ATOMIC_RELAXED,
                                         __HIP_MEMORY_SCOPE_AGENT) < WPG)
                    __builtin_amdgcn_s_sleep(1);
            }
            __syncthreads();
        }
    }
}

extern "C" void kernel_launch(void* const* d_in, const int* in_sizes, int n_in,
                              void* d_out, int out_size, void* d_ws, size_t ws_size,
                              hipStream_t stream) {
    const float* Xt = (const float*)d_in[0];
    const float* W1 = (const float*)d_in[1];
    const float* b1 = (const float*)d_in[2];
    const float* W2 = (const float*)d_in[3];
    const float* b2 = (const float*)d_in[4];
    float* out = (float*)d_out;

    unsigned short* Ybuf = (unsigned short*)d_ws;                    // 512 KB
    unsigned int*   cnt  = (unsigned int*)((char*)d_ws + 4 * BB * HH * 2);
    size_t zero_bytes = (size_t)4 * BB * HH * 2 + (size_t)NGROUP * 1024 * 4;

    hipMemsetAsync(d_ws, 0, zero_bytes, stream);  // zero exchange buffers + counters
    hipLaunchKernelGGL(rnn_fused, dim3(NWG), dim3(256), 0, stream,
                       Xt, W1, b1, W2, b2, out, Ybuf, cnt);
}